// Round 3
// baseline (1450.981 us; speedup 1.0000x reference)
//
#include <hip/hip_runtime.h>
#include <stdint.h>

typedef unsigned short u16;
typedef unsigned short bf16u;
typedef unsigned int u32;
typedef _Float16 f16;
typedef __attribute__((ext_vector_type(8))) short bf16x8;
typedef __attribute__((ext_vector_type(8))) _Float16 f16x8;
typedef __attribute__((ext_vector_type(4))) float f32x4;

#define T_N 2048
#define H_N 2048
#define S_N 1024
#define B_N 2
#define HQ_N 16
#define HKV_N 4
#define D_N 128
#define E_N 32
#define K_TOP 4
#define CAP_N 512
#define IM_N 512
#define SIM_N 1024
#define QD_N 2048
#define KD_N 512
#define NFLAT (T_N*K_TOP)
#define RGRP 128
#define NGRP (NFLAT/RGRP)

// scales (powers of 2, exact)
#define SC_H1   1024.0f
#define SC_W    512.0f
#define SC_QK   2048.0f
#define SC_P    4096.0f
#define SC_V    2048.0f
#define OSC_QKV (1.0f/524288.0f)     // 1/(1024*512)
#define OSC_OPJ (1.0f/1048576.0f)    // 1/(2048*512)

__device__ __forceinline__ float bf2f(bf16u x){ return __uint_as_float(((u32)x)<<16); }
__device__ __forceinline__ bf16u f2bf(float f){
  u32 u = __float_as_uint(f);
  u32 r = (u + 0x7FFFu + ((u>>16)&1u)) >> 16;
  return (bf16u)r;
}
__device__ __forceinline__ void split2h(float x, u16& h, u16& l){
  f16 hh = (f16)x;
  f16 ll = (f16)(x - (float)hh);
  h = __builtin_bit_cast(u16, hh);
  l = __builtin_bit_cast(u16, ll);
}
__device__ __forceinline__ f32x4 mfma16b(bf16x8 a, bf16x8 b, f32x4 c){
  return __builtin_amdgcn_mfma_f32_16x16x32_bf16(a,b,c,0,0,0);
}
__device__ __forceinline__ f32x4 mfma16h(f16x8 a, f16x8 b, f32x4 c){
  return __builtin_amdgcn_mfma_f32_16x16x32_f16(a,b,c,0,0,0);
}
__device__ __forceinline__ void gl_lds16(const void* g, void* l){
  __builtin_amdgcn_global_load_lds((const __attribute__((address_space(1))) u32*)g,
                                   (__attribute__((address_space(3))) u32*)l, 16, 0, 0);
}

// ---------------- transpose + fp32->bf16 (single plane)
__global__ __launch_bounds__(256) void transpose_cvt(const float* __restrict__ in,
                                                     bf16u* __restrict__ out, int R, int C){
  __shared__ bf16u tile[32][33];
  size_t zoff = (size_t)blockIdx.z * R * C;
  const float* ip = in + zoff;
  bf16u* op = out + zoff;
  int rb = blockIdx.x*32, cb = blockIdx.y*32;
  int tx = threadIdx.x, ty = threadIdx.y;
  #pragma unroll
  for (int kk=0;kk<4;kk++)
    tile[ty+kk*8][tx] = f2bf(ip[(size_t)(rb+ty+kk*8)*C + cb + tx]);
  __syncthreads();
  #pragma unroll
  for (int kk=0;kk<4;kk++)
    op[(size_t)(cb+ty+kk*8)*R + rb + tx] = tile[tx][ty+kk*8];
}

// ---------------- transpose + fp16 split (hi/lo), scaled
__global__ __launch_bounds__(256) void transpose_cvt_split16(const float* __restrict__ in,
                                                             u16* __restrict__ oh,
                                                             u16* __restrict__ ol,
                                                             int R, int C, float scale){
  __shared__ u16 th[32][33];
  __shared__ u16 tl[32][33];
  int rb = blockIdx.x*32, cb = blockIdx.y*32;
  int tx = threadIdx.x, ty = threadIdx.y;
  #pragma unroll
  for (int kk=0;kk<4;kk++){
    float x = in[(size_t)(rb+ty+kk*8)*C + cb + tx] * scale;
    u16 hh, ll; split2h(x, hh, ll);
    th[ty+kk*8][tx] = hh; tl[ty+kk*8][tx] = ll;
  }
  __syncthreads();
  #pragma unroll
  for (int kk=0;kk<4;kk++){
    size_t idx = (size_t)(cb+ty+kk*8)*R + rb + tx;
    oh[idx] = th[tx][ty+kk*8];
    ol[idx] = tl[tx][ty+kk*8];
  }
}

// ---------------- RMSNorm fp32 -> bf16 (row=2048)
__global__ __launch_bounds__(256) void rmsnorm_bf16(const float* __restrict__ x,
                                                    const float* __restrict__ w,
                                                    bf16u* __restrict__ y){
  int row = blockIdx.x; int t = threadIdx.x;
  const float4* x4 = (const float4*)(x + (size_t)row*H_N);
  float4 a = x4[2*t], b = x4[2*t+1];
  float ss = a.x*a.x+a.y*a.y+a.z*a.z+a.w*a.w + b.x*b.x+b.y*b.y+b.z*b.z+b.w*b.w;
  #pragma unroll
  for (int m=32;m>=1;m>>=1) ss += __shfl_xor(ss,m,64);
  __shared__ float red[4];
  if ((t&63)==0) red[t>>6]=ss;
  __syncthreads();
  float scale = rsqrtf((red[0]+red[1]+red[2]+red[3])*(1.0f/H_N) + 1e-6f);
  const float4* w4 = (const float4*)w;
  float4 wa = w4[2*t], wb = w4[2*t+1];
  bf16u o0=f2bf(a.x*scale*wa.x), o1=f2bf(a.y*scale*wa.y), o2=f2bf(a.z*scale*wa.z), o3=f2bf(a.w*scale*wa.w);
  bf16u o4=f2bf(b.x*scale*wb.x), o5=f2bf(b.y*scale*wb.y), o6=f2bf(b.z*scale*wb.z), o7=f2bf(b.w*scale*wb.w);
  uint4 pk;
  pk.x = (u32)o0 | ((u32)o1<<16); pk.y = (u32)o2 | ((u32)o3<<16);
  pk.z = (u32)o4 | ((u32)o5<<16); pk.w = (u32)o6 | ((u32)o7<<16);
  ((uint4*)(y + (size_t)row*H_N))[t] = pk;
}

// ---------------- RMSNorm fp32 -> f16 split (scaled SC_H1)
__global__ __launch_bounds__(256) void rmsnorm_f16split(const float* __restrict__ x,
                                                        const float* __restrict__ w,
                                                        u16* __restrict__ yh,
                                                        u16* __restrict__ yl){
  int row = blockIdx.x; int t = threadIdx.x;
  const float4* x4 = (const float4*)(x + (size_t)row*H_N);
  float4 a = x4[2*t], b = x4[2*t+1];
  float ss = a.x*a.x+a.y*a.y+a.z*a.z+a.w*a.w + b.x*b.x+b.y*b.y+b.z*b.z+b.w*b.w;
  #pragma unroll
  for (int m=32;m>=1;m>>=1) ss += __shfl_xor(ss,m,64);
  __shared__ float red[4];
  if ((t&63)==0) red[t>>6]=ss;
  __syncthreads();
  float scale = rsqrtf((red[0]+red[1]+red[2]+red[3])*(1.0f/H_N) + 1e-6f) * SC_H1;
  const float4* w4 = (const float4*)w;
  float4 wa = w4[2*t], wb = w4[2*t+1];
  float o[8] = {a.x*scale*wa.x, a.y*scale*wa.y, a.z*scale*wa.z, a.w*scale*wa.w,
                b.x*scale*wb.x, b.y*scale*wb.y, b.z*scale*wb.z, b.w*scale*wb.w};
  u16 hh[8], ll[8];
  #pragma unroll
  for (int j=0;j<8;j++) split2h(o[j], hh[j], ll[j]);
  uint4 pk, pl;
  pk.x = (u32)hh[0]|((u32)hh[1]<<16); pk.y = (u32)hh[2]|((u32)hh[3]<<16);
  pk.z = (u32)hh[4]|((u32)hh[5]<<16); pk.w = (u32)hh[6]|((u32)hh[7]<<16);
  pl.x = (u32)ll[0]|((u32)ll[1]<<16); pl.y = (u32)ll[2]|((u32)ll[3]<<16);
  pl.z = (u32)ll[4]|((u32)ll[5]<<16); pl.w = (u32)ll[6]|((u32)ll[7]<<16);
  ((uint4*)(yh + (size_t)row*H_N))[t] = pk;
  ((uint4*)(yl + (size_t)row*H_N))[t] = pl;
}

// ---------------- qk-norm + neox RoPE (fp64 trig), f16 split out (scaled SC_QK)
__global__ void qknorm_rope_split(const float* __restrict__ qf, const float* __restrict__ kf,
                                  const float* __restrict__ qw, const float* __restrict__ kw,
                                  const int* __restrict__ positions,
                                  u16* __restrict__ qho, u16* __restrict__ qlo,
                                  u16* __restrict__ kho, u16* __restrict__ klo){
  int t = blockIdx.x; int hy = blockIdx.y; int l = threadIdx.x;
  const float* p; const float* w; u16 *oh, *ol; size_t base;
  if (hy < HQ_N){ base = (size_t)t*QD_N + hy*D_N; p = qf + base; w = qw; oh = qho; ol = qlo; }
  else          { base = (size_t)t*KD_N + (hy-HQ_N)*D_N; p = kf + base; w = kw; oh = kho; ol = klo; }
  float x0 = p[l], x1 = p[l+64];
  float ss = x0*x0 + x1*x1;
  #pragma unroll
  for (int m=32;m>=1;m>>=1) ss += __shfl_xor(ss,m,64);
  float scale = rsqrtf(ss*(1.0f/D_N)+1e-6f);
  x0 *= scale*w[l]; x1 *= scale*w[l+64];
  double freq = exp2(-(double)l * (19.931568569324174/64.0));
  double fr = (double)positions[t] * freq;
  double sd, cd; sincos(fr, &sd, &cd);
  float r0 = (float)((double)x0*cd - (double)x1*sd) * SC_QK;
  float r1 = (float)((double)x1*cd + (double)x0*sd) * SC_QK;
  u16 hh, ll;
  split2h(r0, hh, ll); oh[base+l] = hh; ol[base+l] = ll;
  split2h(r1, hh, ll); oh[base+l+64] = hh; ol[base+l+64] = ll;
}

// ---------------- V transpose + f16 split (scaled SC_V): fp32 [T][512] -> [B*HKV][D][S]
__global__ __launch_bounds__(256) void transpose_v_split(const float* __restrict__ in,
                                                         u16* __restrict__ oh,
                                                         u16* __restrict__ ol){
  __shared__ u16 th[32][33];
  __shared__ u16 tl[32][33];
  int z = blockIdx.z; int b = z >> 2, kvh = z & 3;
  const float* ip = in + (size_t)b*S_N*KD_N + kvh*D_N;
  size_t ob = (size_t)z*D_N*S_N;
  int sb = blockIdx.x*32, db = blockIdx.y*32;
  int tx=threadIdx.x, ty=threadIdx.y;
  #pragma unroll
  for (int kk=0;kk<4;kk++){
    float x = ip[(size_t)(sb+ty+kk*8)*KD_N + db+tx] * SC_V;
    u16 hh, ll; split2h(x, hh, ll);
    th[ty+kk*8][tx] = hh; tl[ty+kk*8][tx] = ll;
  }
  __syncthreads();
  #pragma unroll
  for (int kk=0;kk<4;kk++){
    size_t idx = ob + (size_t)(db+ty+kk*8)*S_N + sb+tx;
    oh[idx] = th[tx][ty+kk*8];
    ol[idx] = tl[tx][ty+kk*8];
  }
}

// ---------------- GEMM: C[M,N] = A[M,K] * BT[N,K]
// SPLIT=true: f16 hi/lo 3-pass. MODE 1: f32 out*oscale (+resid). 2: silu*up bf16 (dual).
// 3: MoE gate/up gather (dual). 4: MoE down atomic scatter.
template<int MODE, bool SPLIT>
__global__ __launch_bounds__(256) void gemm_bt(
    const u16* __restrict__ A, const u16* __restrict__ Al,
    const u16* __restrict__ B0g, const u16* __restrict__ B0lg,
    const u16* __restrict__ B1g,
    void* __restrict__ Cout, const float* __restrict__ resid, float oscale,
    int M, int N, int Kd,
    const int* __restrict__ startsA, const int* __restrict__ countsA,
    const int* __restrict__ perm, const float* __restrict__ permw)
{
  constexpr bool DUAL = (MODE==2 || MODE==3);
  constexpr bool MOE  = (MODE==3 || MODE==4);
  __shared__ u16 As[128*32];
  __shared__ u16 Bs0[128*32];
  __shared__ u16 Asl[SPLIT ? 128*32 : 8];
  __shared__ u16 Bs0l[SPLIT ? 128*32 : 8];
  __shared__ u16 Bs1[DUAL ? 128*32 : 8];

  int tid = threadIdx.x;
  int wave = tid>>6, lane = tid&63, l15 = lane&15, lg = lane>>4;
  int nBase = blockIdx.y*128;

  int e=0, mBase, rows, slotBase=0;
  const u16* Bp0 = B0g; const u16* Bp1 = B1g;
  if constexpr (MOE){
    e = blockIdx.z;
    int cnt = countsA[e]; cnt = cnt < CAP_N ? cnt : CAP_N;
    mBase = blockIdx.x*128;
    rows = cnt - mBase;
    if (rows <= 0) return;
    if (rows > 128) rows = 128;
    slotBase = startsA[e] + mBase;
    Bp0 = B0g + (size_t)e*N*Kd;
    if constexpr (DUAL) Bp1 = B1g + (size_t)e*N*Kd;
  } else { mBase = blockIdx.x*128; rows = 128; }

  size_t aOff[2], bOff[2];
  u16 *aL[2], *b0L[2];
  #pragma unroll
  for (int i=0;i<2;i++){
    int le = (i*256 + tid)*8;
    int r = le >> 5;
    int c = le & 31;
    int rr = (r < rows) ? r : 0;
    size_t arow;
    if constexpr (MODE==3) arow = (size_t)perm[slotBase + rr];
    else if constexpr (MODE==4) arow = (size_t)(slotBase + rr);
    else arow = (size_t)(mBase + rr);
    aOff[i] = arow*Kd + c;
    bOff[i] = (size_t)(nBase + r)*Kd + c;
    aL[i]  = &As [i*2048 + wave*512];
    b0L[i] = &Bs0[i*2048 + wave*512];
  }

  f32x4 zero4 = {0.f,0.f,0.f,0.f};
  f32x4 acc0[4][4];
  f32x4 acc1[DUAL?4:1][DUAL?4:1];
  #pragma unroll
  for (int mi=0;mi<4;mi++)
    #pragma unroll
    for (int ni=0;ni<4;ni++){
      acc0[mi][ni] = zero4;
      if constexpr (DUAL) acc1[mi][ni] = zero4;
    }

  int wm = wave>>1, wn = wave&1;
  int nK = Kd >> 5;
  for (int kt=0; kt<nK; kt++){
    size_t ko = (size_t)kt*32;
    #pragma unroll
    for (int i=0;i<2;i++){
      gl_lds16(A + aOff[i] + ko, aL[i]);
      gl_lds16(Bp0 + bOff[i] + ko, b0L[i]);
      if constexpr (SPLIT){
        gl_lds16(Al + aOff[i] + ko, &Asl[i*2048 + wave*512]);
        gl_lds16(B0lg + bOff[i] + ko, &Bs0l[i*2048 + wave*512]);
      }
      if constexpr (DUAL){
        gl_lds16(Bp1 + bOff[i] + ko, &Bs1[i*2048 + wave*512]);
      }
    }
    __syncthreads();
    if constexpr (SPLIT){
      f16x8 af[4], afl[4];
      #pragma unroll
      for (int mi=0;mi<4;mi++){
        af[mi]  = *(const f16x8*)&As [(wm*64 + mi*16 + l15)*32 + lg*8];
        afl[mi] = *(const f16x8*)&Asl[(wm*64 + mi*16 + l15)*32 + lg*8];
      }
      #pragma unroll
      for (int ni=0;ni<4;ni++){
        f16x8 b0  = *(const f16x8*)&Bs0 [(wn*64 + ni*16 + l15)*32 + lg*8];
        f16x8 b0l = *(const f16x8*)&Bs0l[(wn*64 + ni*16 + l15)*32 + lg*8];
        #pragma unroll
        for (int mi=0;mi<4;mi++){
          acc0[mi][ni] = mfma16h(af[mi], b0, acc0[mi][ni]);
          acc0[mi][ni] = mfma16h(af[mi], b0l, acc0[mi][ni]);
          acc0[mi][ni] = mfma16h(afl[mi], b0, acc0[mi][ni]);
        }
      }
    } else {
      bf16x8 af[4];
      #pragma unroll
      for (int mi=0;mi<4;mi++)
        af[mi] = *(const bf16x8*)&As[(wm*64 + mi*16 + l15)*32 + lg*8];
      #pragma unroll
      for (int ni=0;ni<4;ni++){
        bf16x8 b0 = *(const bf16x8*)&Bs0[(wn*64 + ni*16 + l15)*32 + lg*8];
        #pragma unroll
        for (int mi=0;mi<4;mi++) acc0[mi][ni] = mfma16b(af[mi], b0, acc0[mi][ni]);
        if constexpr (DUAL){
          bf16x8 b1 = *(const bf16x8*)&Bs1[(wn*64 + ni*16 + l15)*32 + lg*8];
          #pragma unroll
          for (int mi=0;mi<4;mi++) acc1[mi][ni] = mfma16b(af[mi], b1, acc1[mi][ni]);
        }
      }
    }
    __syncthreads();
  }

  #pragma unroll
  for (int mi=0;mi<4;mi++){
    #pragma unroll
    for (int ni=0;ni<4;ni++){
      #pragma unroll
      for (int i=0;i<4;i++){
        int rloc = wm*64 + mi*16 + 4*lg + i;
        int col  = nBase + wn*64 + ni*16 + l15;
        float v = acc0[mi][ni][i];
        if constexpr (MODE==1){
          size_t idx = (size_t)(mBase + rloc)*N + col;
          ((float*)Cout)[idx] = v*oscale + (resid ? resid[idx] : 0.0f);
        } else if constexpr (MODE==2){
          float u = acc1[mi][ni][i];
          float sv = v/(1.0f+__expf(-v))*u;
          ((bf16u*)Cout)[(size_t)(mBase + rloc)*N + col] = f2bf(sv);
        } else if constexpr (MODE==3){
          if (rloc < rows){
            float u = acc1[mi][ni][i];
            float sv = v/(1.0f+__expf(-v))*u;
            ((bf16u*)Cout)[(size_t)(slotBase + rloc)*N + col] = f2bf(sv);
          }
        } else {
          if (rloc < rows){
            int slot = slotBase + rloc;
            float wsc = permw[slot];
            int tok = perm[slot];
            atomicAdd(&((float*)Cout)[(size_t)tok*H_N + col], v*wsc);
          }
        }
      }
    }
  }
}

// ---------------- flash attention, causal GQA, f16 split-precision
__global__ __launch_bounds__(256) void attn_kernel(
    const u16* __restrict__ qh, const u16* __restrict__ ql,
    const u16* __restrict__ kh, const u16* __restrict__ kl,
    const u16* __restrict__ vth, const u16* __restrict__ vtl,
    u16* __restrict__ aoh, u16* __restrict__ aol)
{
  int qb = blockIdx.x*64;
  int bh = blockIdx.y;
  int b = bh >> 4, h = bh & 15, kvh = h >> 2;
  int tid = threadIdx.x, wave = tid>>6, lane = tid&63, l15 = lane&15, lg = lane>>4;

  __shared__ u16 Ksh[64*136];
  __shared__ u16 Ksl[64*136];
  __shared__ u16 Vsh[128*72];
  __shared__ u16 Vsl[128*72];
  __shared__ u16 Psh[4][16*72];
  __shared__ u16 Psl[4][16*72];

  size_t qrow = (size_t)(b*S_N + qb + wave*16 + l15)*QD_N + h*D_N;
  f16x8 qfh[4], qfl[4];
  #pragma unroll
  for (int ds=0; ds<4; ds++){
    qfh[ds] = *(const f16x8*)(qh + qrow + ds*32 + lg*8);
    qfl[ds] = *(const f16x8*)(ql + qrow + ds*32 + lg*8);
  }

  f32x4 zero4 = {0.f,0.f,0.f,0.f};
  f32x4 accO[8];
  #pragma unroll
  for (int dc=0; dc<8; dc++) accO[dc] = zero4;
  float mrun[4], lrun[4];
  #pragma unroll
  for (int i=0;i<4;i++){ mrun[i] = -3.0e38f; lrun[i] = 0.0f; }

  const float SC_S = 0.08838834764831845f * (1.0f/(SC_QK*SC_QK));
  int nkt = (qb >> 6) + 1;
  for (int kt=0; kt<nkt; kt++){
    #pragma unroll
    for (int pp=0; pp<4; pp++){
      int r = pp*16 + (tid>>4), c = (tid&15)*8;
      size_t go = (size_t)(b*S_N + kt*64 + r)*KD_N + kvh*D_N + c;
      *(f16x8*)&Ksh[r*136 + c] = *(const f16x8*)(kh + go);
      *(f16x8*)&Ksl[r*136 + c] = *(const f16x8*)(kl + go);
    }
    #pragma unroll
    for (int pp=0; pp<4; pp++){
      int r = pp*32 + (tid>>3), c = (tid&7)*8;
      size_t go = ((size_t)(b*HKV_N + kvh)*D_N + r)*S_N + kt*64 + c;
      *(f16x8*)&Vsh[r*72 + c] = *(const f16x8*)(vth + go);
      *(f16x8*)&Vsl[r*72 + c] = *(const f16x8*)(vtl + go);
    }
    __syncthreads();

    f32x4 sacc[4];
    #pragma unroll
    for (int kc=0;kc<4;kc++){
      sacc[kc] = zero4;
      #pragma unroll
      for (int ds=0; ds<4; ds++){
        f16x8 kfh = *(const f16x8*)&Ksh[(kc*16 + l15)*136 + ds*32 + lg*8];
        f16x8 kfl = *(const f16x8*)&Ksl[(kc*16 + l15)*136 + ds*32 + lg*8];
        sacc[kc] = mfma16h(qfh[ds], kfh, sacc[kc]);
        sacc[kc] = mfma16h(qfh[ds], kfl, sacc[kc]);
        sacc[kc] = mfma16h(qfl[ds], kfh, sacc[kc]);
      }
    }

    float pv[4][4];
    bool last = (kt == nkt-1);
    #pragma unroll
    for (int kc=0;kc<4;kc++)
      #pragma unroll
      for (int i=0;i<4;i++){
        float sv = sacc[kc][i] * SC_S;
        if (last){
          int kg = kt*64 + kc*16 + l15;
          int qg = qb + wave*16 + 4*lg + i;
          if (kg > qg) sv = -3.0e38f;
        }
        pv[kc][i] = sv;
      }

    #pragma unroll
    for (int i=0;i<4;i++){
      float mx = fmaxf(fmaxf(pv[0][i],pv[1][i]),fmaxf(pv[2][i],pv[3][i]));
      #pragma unroll
      for (int mm=1; mm<16; mm<<=1) mx = fmaxf(mx, __shfl_xor(mx, mm, 64));
      float mnew = fmaxf(mrun[i], mx);
      float corr = exp2f((mrun[i]-mnew)*1.44269504f);
      float ps = 0.f;
      #pragma unroll
      for (int kc=0;kc<4;kc++){
        float p = exp2f((pv[kc][i]-mnew)*1.44269504f);
        pv[kc][i] = p; ps += p;
      }
      #pragma unroll
      for (int mm=1; mm<16; mm<<=1) ps += __shfl_xor(ps, mm, 64);
      lrun[i] = lrun[i]*corr + ps;
      mrun[i] = mnew;
      #pragma unroll
      for (int dc=0;dc<8;dc++) accO[dc][i] *= corr;
    }

    #pragma unroll
    for (int kc=0;kc<4;kc++)
      #pragma unroll
      for (int i=0;i<4;i++){
        u16 hh, ll; split2h(pv[kc][i]*SC_P, hh, ll);
        Psh[wave][(4*lg+i)*72 + kc*16 + l15] = hh;
        Psl[wave][(4*lg+i)*72 + kc*16 + l15] = ll;
      }
    asm volatile("s_waitcnt lgkmcnt(0)" ::: "memory");
    __builtin_amdgcn_sched_barrier(0);

    #pragma unroll
    for (int ks=0; ks<2; ks++){
      f16x8 pfh = *(const f16x8*)&Psh[wave][l15*72 + ks*32 + lg*8];
      f16x8 pfl = *(const f16x8*)&Psl[wave][l15*72 + ks*32 + lg*8];
      #pragma unroll
      for (int dc=0; dc<8; dc++){
        f16x8 vfh = *(const f16x8*)&Vsh[(dc*16 + l15)*72 + ks*32 + lg*8];
        f16x8 vfl = *(const f16x8*)&Vsl[(dc*16 + l15)*72 + ks*32 + lg*8];
        accO[dc] = mfma16h(pfh, vfh, accO[dc]);
        accO[dc] = mfma16h(pfh, vfl, accO[dc]);
        accO[dc] = mfma16h(pfl, vfh, accO[dc]);
      }
    }
    __syncthreads();
  }

  // accO is scaled by SC_P*SC_V = 2^23; store ao*SC_QK(2048) halves => accO/(4096*lrun)
  #pragma unroll
  for (int i=0;i<4;i++){
    float inv = 1.0f / (4096.0f * lrun[i]);
    size_t orow = (size_t)(b*S_N + qb + wave*16 + 4*lg + i)*QD_N + h*D_N;
    #pragma unroll
    for (int dc=0; dc<8; dc++){
      u16 hh, ll; split2h(accO[dc][i]*inv, hh, ll);
      aoh[orow + dc*16 + l15] = hh;
      aol[orow + dc*16 + l15] = ll;
    }
  }
}

// ---------------- router: fp32 rms-norm + dot + sigmoid + top-4
__global__ __launch_bounds__(256) void router_kernel(
    const float* __restrict__ resid2, const float* __restrict__ ln2w,
    const float* __restrict__ gw, const float* __restrict__ ebias,
    int* __restrict__ tkIdx, float* __restrict__ tkW, int* __restrict__ counts)
{
  int t = blockIdx.x, tid = threadIdx.x;
  __shared__ float xs[H_N];
  __shared__ float red[4];
  __shared__ float sc[E_N];
  const float4* x4 = (const float4*)(resid2 + (size_t)t*H_N);
  float4 a = x4[2*tid], b = x4[2*tid+1];
  float ss = a.x*a.x+a.y*a.y+a.z*a.z+a.w*a.w + b.x*b.x+b.y*b.y+b.z*b.z+b.w*b.w;
  #pragma unroll
  for (int m=32;m>=1;m>>=1) ss += __shfl_xor(ss,m,64);
  if ((tid&63)==0) red[tid>>6]=ss;
  __syncthreads();
  float scale = rsqrtf((red[0]+red[1]+red[2]+red[3])*(1.0f/H_N) + 1e-6f);
  const float4* w4 = (const float4*)ln2w;
  float4 wa = w4[2*tid], wb = w4[2*tid+1];
  xs[tid*8+0]=a.x*scale*wa.x; xs[tid*8+1]=a.y*scale*wa.y;
  xs[tid*8+2]=a.z*scale*wa.z; xs[tid*8+3]=a.w*scale*wa.w;
  xs[tid*8+4]=b.x*scale*wb.x; xs[tid*8+5]=b.y*scale*wb.y;
  xs[tid*8+6]=b.z*scale*wb.z; xs[tid*8+7]=b.w*scale*wb.w;
  __syncthreads();
  int wave = tid>>6, lane = tid&63;
  for (int e = wave; e < E_N; e += 4){
    float acc = 0.f;
    for (int kk = lane; kk < H_N; kk += 64) acc += xs[kk]*gw[(size_t)kk*E_N + e];
    #pragma unroll
    for (int m=32;m>=1;m>>=1) acc += __shfl_xor(acc,m,64);
    if (lane==0) sc[e] = 1.0f/(1.0f+__expf(-acc));
  }
  __syncthreads();
  if (tid==0){
    float sb[E_N];
    #pragma unroll
    for (int e2=0;e2<E_N;e2++) sb[e2] = sc[e2]+ebias[e2];
    int ch[4]; float wv[4]; float wsum=0.f;
    for (int j=0;j<4;j++){
      int best=0; float bv=-3.0e38f;
      for (int e2=0;e2<E_N;e2++) if (sb[e2] > bv){ bv=sb[e2]; best=e2; }
      ch[j]=best; wv[j]=sc[best]; wsum+=sc[best]; sb[best]=-3.0e38f;
    }
    float invs = 1.0f/wsum;
    for (int j=0;j<4;j++){
      tkIdx[t*4+j]=ch[j]; tkW[t*4+j]=wv[j]*invs;
      atomicAdd(&counts[ch[j]], 1);
    }
  }
}

// ---------------- deterministic capacity ranking (stable order by flat index)
__global__ void moe_count_kernel(const int* __restrict__ tki, int* __restrict__ G){
  __shared__ int cnt[E_N];
  int g = blockIdx.x, t = threadIdx.x;
  if (t < E_N) cnt[t] = 0;
  __syncthreads();
  atomicAdd(&cnt[tki[g*RGRP + t]], 1);
  __syncthreads();
  if (t < E_N) G[g*E_N + t] = cnt[t];
}

__global__ void moe_scan_kernel(const int* __restrict__ G, int* __restrict__ base,
                                int* __restrict__ starts){
  __shared__ int tot[E_N];
  int e = threadIdx.x;
  if (e < E_N){
    int run = 0;
    for (int g=0; g<NGRP; g++){ base[g*E_N+e] = run; run += G[g*E_N+e]; }
    tot[e] = run < CAP_N ? run : CAP_N;
  }
  __syncthreads();
  if (e==0){
    int run=0;
    for (int x=0; x<E_N; x++){ starts[x]=run; run+=tot[x]; }
  }
}

__global__ void moe_assign_kernel(const int* __restrict__ tki, const float* __restrict__ tkw,
                                  const int* __restrict__ base, const int* __restrict__ starts,
                                  int* __restrict__ ptok, float* __restrict__ pw){
  __shared__ int eL[RGRP];
  int g = blockIdx.x, t = threadIdx.x;
  int f = g*RGRP + t;
  int e = tki[f];
  eL[t] = e;
  __syncthreads();
  int r = 0;
  for (int j=0; j<RGRP; j++) r += ((j < t) && (eL[j]==e)) ? 1 : 0;
  int pos = base[g*E_N + e] + r;
  if (pos < CAP_N){
    int slot = starts[e] + pos;
    ptok[slot] = f >> 2;
    pw[slot] = tkw[f];
  }
}

extern "C" void kernel_launch(void* const* d_in, const int* in_sizes, int n_in,
                              void* d_out, int out_size, void* d_ws, size_t ws_size,
                              hipStream_t stream) {
  (void)in_sizes; (void)n_in; (void)out_size; (void)ws_size;
  const float* hidden    = (const float*)d_in[0];
  const int*   positions = (const int*)d_in[1];
  const float* ln1w = (const float*)d_in[2];
  const float* ln2w = (const float*)d_in[3];
  const float* wq   = (const float*)d_in[4];
  const float* wk   = (const float*)d_in[5];
  const float* wv   = (const float*)d_in[6];
  const float* wo   = (const float*)d_in[7];
  const float* qnw  = (const float*)d_in[8];
  const float* knw  = (const float*)d_in[9];
  const float* gatew= (const float*)d_in[10];
  const float* ebias= (const float*)d_in[11];
  const float* wge  = (const float*)d_in[12];
  const float* wue  = (const float*)d_in[13];
  const float* wde  = (const float*)d_in[14];
  const float* wsg  = (const float*)d_in[15];
  const float* wsu  = (const float*)d_in[16];
  const float* wsd  = (const float*)d_in[17];
  float* outp = (float*)d_out;

  char* wsb = (char*)d_ws;
  size_t off = 0;
  auto take = [&](size_t bytes)->char*{
    char* p = wsb + off; off += (bytes + 255) & ~(size_t)255; return p;
  };
  u16* wqTh = (u16*)take(2048ull*2048*2);
  u16* wqTl = (u16*)take(2048ull*2048*2);
  u16* wkTh = (u16*)take(512ull*2048*2);
  u16* wkTl = (u16*)take(512ull*2048*2);
  u16* wvTh = (u16*)take(512ull*2048*2);
  u16* wvTl = (u16*)take(512ull*2048*2);
  u16* woTh = (u16*)take(2048ull*2048*2);
  u16* woTl = (u16*)take(2048ull*2048*2);
  u16* wsgT = (u16*)take(1024ull*2048*2);
  u16* wsuT = (u16*)take(1024ull*2048*2);
  u16* wsdT = (u16*)take(2048ull*1024*2);
  u16* wgeT = (u16*)take(32ull*512*2048*2);
  u16* wueT = (u16*)take(32ull*512*2048*2);
  u16* wdeT = (u16*)take(32ull*2048*512*2);
  u16* h1h  = (u16*)take((size_t)T_N*H_N*2);
  u16* h1l  = (u16*)take((size_t)T_N*H_N*2);
  float* qf32 = (float*)take((size_t)T_N*QD_N*4);
  float* kf32 = (float*)take((size_t)T_N*KD_N*4);
  float* vf32 = (float*)take((size_t)T_N*KD_N*4);
  u16* qHh  = (u16*)take((size_t)T_N*QD_N*2);
  u16* qHl  = (u16*)take((size_t)T_N*QD_N*2);
  u16* kHh  = (u16*)take((size_t)T_N*KD_N*2);
  u16* kHl  = (u16*)take((size_t)T_N*KD_N*2);
  u16* vtHh = (u16*)take((size_t)T_N*KD_N*2);
  u16* vtHl = (u16*)take((size_t)T_N*KD_N*2);
  u16* aoh  = (u16*)take((size_t)T_N*QD_N*2);
  u16* aol  = (u16*)take((size_t)T_N*QD_N*2);
  float* resid2=(float*)take((size_t)T_N*H_N*4);
  u16* h2   = (u16*)take((size_t)T_N*H_N*2);
  u16* interS=(u16*)take((size_t)T_N*SIM_N*2);
  u16* minter=(u16*)take((size_t)T_N*K_TOP*IM_N*2);
  int*   tki  = (int*)take((size_t)NFLAT*4);
  float* tkw  = (float*)take((size_t)NFLAT*4);
  int*   counts=(int*)take(E_N*4);
  int*   Gcnt = (int*)take((size_t)NGRP*E_N*4);
  int*   Gbase= (int*)take((size_t)NGRP*E_N*4);
  int*   starts=(int*)take(E_N*4);
  int*   ptok = (int*)take((size_t)NFLAT*4);
  float* pw   = (float*)take((size_t)NFLAT*4);

  hipMemsetAsync(counts, 0, 256, stream);

  dim3 tb(32,8);
  transpose_cvt_split16<<<dim3(64,64,1), tb, 0, stream>>>(wq, wqTh, wqTl, 2048, 2048, SC_W);
  transpose_cvt_split16<<<dim3(64,16,1), tb, 0, stream>>>(wk, wkTh, wkTl, 2048, 512, SC_W);
  transpose_cvt_split16<<<dim3(64,16,1), tb, 0, stream>>>(wv, wvTh, wvTl, 2048, 512, SC_W);
  transpose_cvt_split16<<<dim3(64,64,1), tb, 0, stream>>>(wo, woTh, woTl, 2048, 2048, SC_W);
  transpose_cvt<<<dim3(64,32,1), tb, 0, stream>>>(wsg, (bf16u*)wsgT, 2048, 1024);
  transpose_cvt<<<dim3(64,32,1), tb, 0, stream>>>(wsu, (bf16u*)wsuT, 2048, 1024);
  transpose_cvt<<<dim3(32,64,1), tb, 0, stream>>>(wsd, (bf16u*)wsdT, 1024, 2048);
  transpose_cvt<<<dim3(64,16,32), tb, 0, stream>>>(wge, (bf16u*)wgeT, 2048, 512);
  transpose_cvt<<<dim3(64,16,32), tb, 0, stream>>>(wue, (bf16u*)wueT, 2048, 512);
  transpose_cvt<<<dim3(16,64,32), tb, 0, stream>>>(wde, (bf16u*)wdeT, 512, 2048);

  rmsnorm_f16split<<<T_N, 256, 0, stream>>>(hidden, ln1w, h1h, h1l);
  gemm_bt<1,true><<<dim3(16,16), 256, 0, stream>>>(h1h, h1l, wqTh, wqTl, nullptr, qf32, nullptr, OSC_QKV, T_N, QD_N, H_N, nullptr,nullptr,nullptr,nullptr);
  gemm_bt<1,true><<<dim3(16,4),  256, 0, stream>>>(h1h, h1l, wkTh, wkTl, nullptr, kf32, nullptr, OSC_QKV, T_N, KD_N, H_N, nullptr,nullptr,nullptr,nullptr);
  gemm_bt<1,true><<<dim3(16,4),  256, 0, stream>>>(h1h, h1l, wvTh, wvTl, nullptr, vf32, nullptr, OSC_QKV, T_N, KD_N, H_N, nullptr,nullptr,nullptr,nullptr);
  qknorm_rope_split<<<dim3(T_N,20), 64, 0, stream>>>(qf32, kf32, qnw, knw, positions, qHh, qHl, kHh, kHl);
  transpose_v_split<<<dim3(32,4,8), tb, 0, stream>>>(vf32, vtHh, vtHl);
  attn_kernel<<<dim3(16,32), 256, 0, stream>>>(qHh, qHl, kHh, kHl, vtHh, vtHl, aoh, aol);
  gemm_bt<1,true><<<dim3(16,16), 256, 0, stream>>>(aoh, aol, woTh, woTl, nullptr, resid2, hidden, OSC_OPJ, T_N, H_N, QD_N, nullptr,nullptr,nullptr,nullptr);
  rmsnorm_bf16<<<T_N, 256, 0, stream>>>(resid2, ln2w, (bf16u*)h2);
  gemm_bt<2,false><<<dim3(16,8), 256, 0, stream>>>(h2, nullptr, wsgT, nullptr, wsuT, interS, nullptr, 1.0f, T_N, SIM_N, H_N, nullptr,nullptr,nullptr,nullptr);
  gemm_bt<1,false><<<dim3(16,16), 256, 0, stream>>>(interS, nullptr, wsdT, nullptr, nullptr, outp, resid2, 1.0f, T_N, H_N, SIM_N, nullptr,nullptr,nullptr,nullptr);
  router_kernel<<<T_N, 256, 0, stream>>>(resid2, ln2w, gatew, ebias, tki, tkw, counts);
  moe_count_kernel<<<NGRP, RGRP, 0, stream>>>(tki, Gcnt);
  moe_scan_kernel<<<1, 64, 0, stream>>>(Gcnt, Gbase, starts);
  moe_assign_kernel<<<NGRP, RGRP, 0, stream>>>(tki, tkw, Gbase, starts, ptok, pw);
  gemm_bt<3,false><<<dim3(4,4,32), 256, 0, stream>>>(h2, nullptr, wgeT, nullptr, wueT, minter, nullptr, 1.0f, 0, IM_N, H_N, starts, counts, ptok, nullptr);
  gemm_bt<4,false><<<dim3(4,16,32), 256, 0, stream>>>(minter, nullptr, wdeT, nullptr, nullptr, outp, nullptr, 1.0f, 0, H_N, IM_N, starts, counts, ptok, pw);
}

// Round 4
// 984.566 us; speedup vs baseline: 1.4737x; 1.4737x over previous
//
#include <hip/hip_runtime.h>
#include <stdint.h>

typedef unsigned short u16;
typedef unsigned short bf16u;
typedef unsigned int u32;
typedef _Float16 f16;
typedef __attribute__((ext_vector_type(8))) short bf16x8;
typedef __attribute__((ext_vector_type(8))) _Float16 f16x8;
typedef __attribute__((ext_vector_type(4))) float f32x4;

#define T_N 2048
#define H_N 2048
#define S_N 1024
#define B_N 2
#define HQ_N 16
#define HKV_N 4
#define D_N 128
#define E_N 32
#define K_TOP 4
#define CAP_N 512
#define IM_N 512
#define SIM_N 1024
#define QD_N 2048
#define KD_N 512
#define QKV_N 3072
#define NFLAT (T_N*K_TOP)
#define RGRP 128
#define NGRP (NFLAT/RGRP)

// scales (powers of 2, exact)
#define SC_H1   1024.0f
#define SC_W    512.0f
#define SC_QK   2048.0f
#define SC_P    4096.0f
#define SC_V    2048.0f
#define OSC_QKV (1.0f/524288.0f)     // 1/(1024*512)
#define OSC_OPJ (1.0f/1048576.0f)    // 1/(2048*512)

__device__ __forceinline__ float bf2f(bf16u x){ return __uint_as_float(((u32)x)<<16); }
__device__ __forceinline__ bf16u f2bf(float f){
  u32 u = __float_as_uint(f);
  u32 r = (u + 0x7FFFu + ((u>>16)&1u)) >> 16;
  return (bf16u)r;
}
__device__ __forceinline__ void split2h(float x, u16& h, u16& l){
  f16 hh = (f16)x;
  f16 ll = (f16)(x - (float)hh);
  h = __builtin_bit_cast(u16, hh);
  l = __builtin_bit_cast(u16, ll);
}
__device__ __forceinline__ f32x4 mfma16b(bf16x8 a, bf16x8 b, f32x4 c){
  return __builtin_amdgcn_mfma_f32_16x16x32_bf16(a,b,c,0,0,0);
}
__device__ __forceinline__ f32x4 mfma16h(f16x8 a, f16x8 b, f32x4 c){
  return __builtin_amdgcn_mfma_f32_16x16x32_f16(a,b,c,0,0,0);
}
__device__ __forceinline__ void gl_lds16(const void* g, void* l){
  __builtin_amdgcn_global_load_lds((const __attribute__((address_space(1))) u32*)g,
                                   (__attribute__((address_space(3))) u32*)l, 16, 0, 0);
}

// ---------------- fp32 transpose (small, for gate_w)
__global__ __launch_bounds__(256) void transpose_f32(const float* __restrict__ in,
                                                     float* __restrict__ out, int R, int C){
  __shared__ float tile[32][33];
  int rb = blockIdx.x*32, cb = blockIdx.y*32;
  int tx = threadIdx.x, ty = threadIdx.y;
  #pragma unroll
  for (int kk=0;kk<4;kk++)
    tile[ty+kk*8][tx] = in[(size_t)(rb+ty+kk*8)*C + cb + tx];
  __syncthreads();
  #pragma unroll
  for (int kk=0;kk<4;kk++)
    out[(size_t)(cb+ty+kk*8)*R + rb + tx] = tile[tx][ty+kk*8];
}

// ---------------- transpose + fp32->bf16 (single plane)
__global__ __launch_bounds__(256) void transpose_cvt(const float* __restrict__ in,
                                                     bf16u* __restrict__ out, int R, int C){
  __shared__ bf16u tile[32][33];
  size_t zoff = (size_t)blockIdx.z * R * C;
  const float* ip = in + zoff;
  bf16u* op = out + zoff;
  int rb = blockIdx.x*32, cb = blockIdx.y*32;
  int tx = threadIdx.x, ty = threadIdx.y;
  #pragma unroll
  for (int kk=0;kk<4;kk++)
    tile[ty+kk*8][tx] = f2bf(ip[(size_t)(rb+ty+kk*8)*C + cb + tx]);
  __syncthreads();
  #pragma unroll
  for (int kk=0;kk<4;kk++)
    op[(size_t)(cb+ty+kk*8)*R + rb + tx] = tile[tx][ty+kk*8];
}

// ---------------- transpose + fp16 split (hi/lo), scaled
__global__ __launch_bounds__(256) void transpose_cvt_split16(const float* __restrict__ in,
                                                             u16* __restrict__ oh,
                                                             u16* __restrict__ ol,
                                                             int R, int C, float scale){
  __shared__ u16 th[32][33];
  __shared__ u16 tl[32][33];
  int rb = blockIdx.x*32, cb = blockIdx.y*32;
  int tx = threadIdx.x, ty = threadIdx.y;
  #pragma unroll
  for (int kk=0;kk<4;kk++){
    float x = in[(size_t)(rb+ty+kk*8)*C + cb + tx] * scale;
    u16 hh, ll; split2h(x, hh, ll);
    th[ty+kk*8][tx] = hh; tl[ty+kk*8][tx] = ll;
  }
  __syncthreads();
  #pragma unroll
  for (int kk=0;kk<4;kk++){
    size_t idx = (size_t)(cb+ty+kk*8)*R + rb + tx;
    oh[idx] = th[tx][ty+kk*8];
    ol[idx] = tl[tx][ty+kk*8];
  }
}

// ---------------- RMSNorm fp32 -> bf16 (row=2048)
__global__ __launch_bounds__(256) void rmsnorm_bf16(const float* __restrict__ x,
                                                    const float* __restrict__ w,
                                                    bf16u* __restrict__ y){
  int row = blockIdx.x; int t = threadIdx.x;
  const float4* x4 = (const float4*)(x + (size_t)row*H_N);
  float4 a = x4[2*t], b = x4[2*t+1];
  float ss = a.x*a.x+a.y*a.y+a.z*a.z+a.w*a.w + b.x*b.x+b.y*b.y+b.z*b.z+b.w*b.w;
  #pragma unroll
  for (int m=32;m>=1;m>>=1) ss += __shfl_xor(ss,m,64);
  __shared__ float red[4];
  if ((t&63)==0) red[t>>6]=ss;
  __syncthreads();
  float scale = rsqrtf((red[0]+red[1]+red[2]+red[3])*(1.0f/H_N) + 1e-6f);
  const float4* w4 = (const float4*)w;
  float4 wa = w4[2*t], wb = w4[2*t+1];
  bf16u o0=f2bf(a.x*scale*wa.x), o1=f2bf(a.y*scale*wa.y), o2=f2bf(a.z*scale*wa.z), o3=f2bf(a.w*scale*wa.w);
  bf16u o4=f2bf(b.x*scale*wb.x), o5=f2bf(b.y*scale*wb.y), o6=f2bf(b.z*scale*wb.z), o7=f2bf(b.w*scale*wb.w);
  uint4 pk;
  pk.x = (u32)o0 | ((u32)o1<<16); pk.y = (u32)o2 | ((u32)o3<<16);
  pk.z = (u32)o4 | ((u32)o5<<16); pk.w = (u32)o6 | ((u32)o7<<16);
  ((uint4*)(y + (size_t)row*H_N))[t] = pk;
}

// ---------------- RMSNorm fp32 -> f16 split (scaled SC_H1)
__global__ __launch_bounds__(256) void rmsnorm_f16split(const float* __restrict__ x,
                                                        const float* __restrict__ w,
                                                        u16* __restrict__ yh,
                                                        u16* __restrict__ yl){
  int row = blockIdx.x; int t = threadIdx.x;
  const float4* x4 = (const float4*)(x + (size_t)row*H_N);
  float4 a = x4[2*t], b = x4[2*t+1];
  float ss = a.x*a.x+a.y*a.y+a.z*a.z+a.w*a.w + b.x*b.x+b.y*b.y+b.z*b.z+b.w*b.w;
  #pragma unroll
  for (int m=32;m>=1;m>>=1) ss += __shfl_xor(ss,m,64);
  __shared__ float red[4];
  if ((t&63)==0) red[t>>6]=ss;
  __syncthreads();
  float scale = rsqrtf((red[0]+red[1]+red[2]+red[3])*(1.0f/H_N) + 1e-6f) * SC_H1;
  const float4* w4 = (const float4*)w;
  float4 wa = w4[2*t], wb = w4[2*t+1];
  float o[8] = {a.x*scale*wa.x, a.y*scale*wa.y, a.z*scale*wa.z, a.w*scale*wa.w,
                b.x*scale*wb.x, b.y*scale*wb.y, b.z*scale*wb.z, b.w*scale*wb.w};
  u16 hh[8], ll[8];
  #pragma unroll
  for (int j=0;j<8;j++) split2h(o[j], hh[j], ll[j]);
  uint4 pk, pl;
  pk.x = (u32)hh[0]|((u32)hh[1]<<16); pk.y = (u32)hh[2]|((u32)hh[3]<<16);
  pk.z = (u32)hh[4]|((u32)hh[5]<<16); pk.w = (u32)hh[6]|((u32)hh[7]<<16);
  pl.x = (u32)ll[0]|((u32)ll[1]<<16); pl.y = (u32)ll[2]|((u32)ll[3]<<16);
  pl.z = (u32)ll[4]|((u32)ll[5]<<16); pl.w = (u32)ll[6]|((u32)ll[7]<<16);
  ((uint4*)(yh + (size_t)row*H_N))[t] = pk;
  ((uint4*)(yl + (size_t)row*H_N))[t] = pl;
}

// ---------------- qk-norm + neox RoPE (fp64 trig), reads fused qkv32, f16 split out
__global__ void qknorm_rope_split(const float* __restrict__ qkv,
                                  const float* __restrict__ qw, const float* __restrict__ kw,
                                  const int* __restrict__ positions,
                                  u16* __restrict__ qho, u16* __restrict__ qlo,
                                  u16* __restrict__ kho, u16* __restrict__ klo){
  int t = blockIdx.x; int hy = blockIdx.y; int l = threadIdx.x;
  const float* p; const float* w; u16 *oh, *ol; size_t obase;
  if (hy < HQ_N){
    p = qkv + (size_t)t*QKV_N + hy*D_N; w = qw;
    oh = qho; ol = qlo; obase = (size_t)t*QD_N + hy*D_N;
  } else {
    p = qkv + (size_t)t*QKV_N + QD_N + (hy-HQ_N)*D_N; w = kw;
    oh = kho; ol = klo; obase = (size_t)t*KD_N + (hy-HQ_N)*D_N;
  }
  float x0 = p[l], x1 = p[l+64];
  float ss = x0*x0 + x1*x1;
  #pragma unroll
  for (int m=32;m>=1;m>>=1) ss += __shfl_xor(ss,m,64);
  float scale = rsqrtf(ss*(1.0f/D_N)+1e-6f);
  x0 *= scale*w[l]; x1 *= scale*w[l+64];
  double freq = exp2(-(double)l * (19.931568569324174/64.0));
  double fr = (double)positions[t] * freq;
  double sd, cd; sincos(fr, &sd, &cd);
  float r0 = (float)((double)x0*cd - (double)x1*sd) * SC_QK;
  float r1 = (float)((double)x1*cd + (double)x0*sd) * SC_QK;
  u16 hh, ll;
  split2h(r0, hh, ll); oh[obase+l] = hh; ol[obase+l] = ll;
  split2h(r1, hh, ll); oh[obase+l+64] = hh; ol[obase+l+64] = ll;
}

// ---------------- V transpose + f16 split (scaled SC_V): qkv32 [T][3072] v-cols -> [B*HKV][D][S]
__global__ __launch_bounds__(256) void transpose_v_split(const float* __restrict__ in,
                                                         u16* __restrict__ oh,
                                                         u16* __restrict__ ol){
  __shared__ u16 th[32][33];
  __shared__ u16 tl[32][33];
  int z = blockIdx.z; int b = z >> 2, kvh = z & 3;
  const float* ip = in + (size_t)b*S_N*QKV_N + QD_N + KD_N + kvh*D_N;
  size_t ob = (size_t)z*D_N*S_N;
  int sb = blockIdx.x*32, db = blockIdx.y*32;
  int tx=threadIdx.x, ty=threadIdx.y;
  #pragma unroll
  for (int kk=0;kk<4;kk++){
    float x = ip[(size_t)(sb+ty+kk*8)*QKV_N + db+tx] * SC_V;
    u16 hh, ll; split2h(x, hh, ll);
    th[ty+kk*8][tx] = hh; tl[ty+kk*8][tx] = ll;
  }
  __syncthreads();
  #pragma unroll
  for (int kk=0;kk<4;kk++){
    size_t idx = ob + (size_t)(db+ty+kk*8)*S_N + sb+tx;
    oh[idx] = th[tx][ty+kk*8];
    ol[idx] = tl[tx][ty+kk*8];
  }
}

// ---------------- GEMM: C[M,N] = A[M,K] * BT[N,K]
// SPLIT=true: f16 hi/lo 3-pass. MODE 1: f32 out*oscale (+resid). 2: silu*up bf16 (dual).
// 3: MoE gate/up gather (dual). 4: MoE down -> obuf bf16 (no atomics).
template<int MODE, bool SPLIT>
__global__ __launch_bounds__(256) void gemm_bt(
    const u16* __restrict__ A, const u16* __restrict__ Al,
    const u16* __restrict__ B0g, const u16* __restrict__ B0lg,
    const u16* __restrict__ B1g,
    void* __restrict__ Cout, const float* __restrict__ resid, float oscale,
    int M, int N, int Kd,
    const int* __restrict__ startsA, const int* __restrict__ countsA,
    const int* __restrict__ perm)
{
  constexpr bool DUAL = (MODE==2 || MODE==3);
  constexpr bool MOE  = (MODE==3 || MODE==4);
  __shared__ u16 As[128*32];
  __shared__ u16 Bs0[128*32];
  __shared__ u16 Asl[SPLIT ? 128*32 : 8];
  __shared__ u16 Bs0l[SPLIT ? 128*32 : 8];
  __shared__ u16 Bs1[DUAL ? 128*32 : 8];

  int tid = threadIdx.x;
  int wave = tid>>6, lane = tid&63, l15 = lane&15, lg = lane>>4;
  int nBase = blockIdx.y*128;

  int e=0, mBase, rows, slotBase=0;
  const u16* Bp0 = B0g; const u16* Bp1 = B1g;
  if constexpr (MOE){
    e = blockIdx.z;
    int cnt = countsA[e]; cnt = cnt < CAP_N ? cnt : CAP_N;
    mBase = blockIdx.x*128;
    rows = cnt - mBase;
    if (rows <= 0) return;
    if (rows > 128) rows = 128;
    slotBase = startsA[e] + mBase;
    Bp0 = B0g + (size_t)e*N*Kd;
    if constexpr (DUAL) Bp1 = B1g + (size_t)e*N*Kd;
  } else { mBase = blockIdx.x*128; rows = 128; }

  size_t aOff[2], bOff[2];
  u16 *aL[2], *b0L[2];
  #pragma unroll
  for (int i=0;i<2;i++){
    int le = (i*256 + tid)*8;
    int r = le >> 5;
    int c = le & 31;
    int rr = (r < rows) ? r : 0;
    size_t arow;
    if constexpr (MODE==3) arow = (size_t)perm[slotBase + rr];
    else if constexpr (MODE==4) arow = (size_t)(slotBase + rr);
    else arow = (size_t)(mBase + rr);
    aOff[i] = arow*Kd + c;
    bOff[i] = (size_t)(nBase + r)*Kd + c;
    aL[i]  = &As [i*2048 + wave*512];
    b0L[i] = &Bs0[i*2048 + wave*512];
  }

  f32x4 zero4 = {0.f,0.f,0.f,0.f};
  f32x4 acc0[4][4];
  f32x4 acc1[DUAL?4:1][DUAL?4:1];
  #pragma unroll
  for (int mi=0;mi<4;mi++)
    #pragma unroll
    for (int ni=0;ni<4;ni++){
      acc0[mi][ni] = zero4;
      if constexpr (DUAL) acc1[mi][ni] = zero4;
    }

  int wm = wave>>1, wn = wave&1;
  int nK = Kd >> 5;
  for (int kt=0; kt<nK; kt++){
    size_t ko = (size_t)kt*32;
    #pragma unroll
    for (int i=0;i<2;i++){
      gl_lds16(A + aOff[i] + ko, aL[i]);
      gl_lds16(Bp0 + bOff[i] + ko, b0L[i]);
      if constexpr (SPLIT){
        gl_lds16(Al + aOff[i] + ko, &Asl[i*2048 + wave*512]);
        gl_lds16(B0lg + bOff[i] + ko, &Bs0l[i*2048 + wave*512]);
      }
      if constexpr (DUAL){
        gl_lds16(Bp1 + bOff[i] + ko, &Bs1[i*2048 + wave*512]);
      }
    }
    __syncthreads();
    if constexpr (SPLIT){
      f16x8 af[4], afl[4];
      #pragma unroll
      for (int mi=0;mi<4;mi++){
        af[mi]  = *(const f16x8*)&As [(wm*64 + mi*16 + l15)*32 + lg*8];
        afl[mi] = *(const f16x8*)&Asl[(wm*64 + mi*16 + l15)*32 + lg*8];
      }
      #pragma unroll
      for (int ni=0;ni<4;ni++){
        f16x8 b0  = *(const f16x8*)&Bs0 [(wn*64 + ni*16 + l15)*32 + lg*8];
        f16x8 b0l = *(const f16x8*)&Bs0l[(wn*64 + ni*16 + l15)*32 + lg*8];
        #pragma unroll
        for (int mi=0;mi<4;mi++){
          acc0[mi][ni] = mfma16h(af[mi], b0, acc0[mi][ni]);
          acc0[mi][ni] = mfma16h(af[mi], b0l, acc0[mi][ni]);
          acc0[mi][ni] = mfma16h(afl[mi], b0, acc0[mi][ni]);
        }
      }
    } else {
      bf16x8 af[4];
      #pragma unroll
      for (int mi=0;mi<4;mi++)
        af[mi] = *(const bf16x8*)&As[(wm*64 + mi*16 + l15)*32 + lg*8];
      #pragma unroll
      for (int ni=0;ni<4;ni++){
        bf16x8 b0 = *(const bf16x8*)&Bs0[(wn*64 + ni*16 + l15)*32 + lg*8];
        #pragma unroll
        for (int mi=0;mi<4;mi++) acc0[mi][ni] = mfma16b(af[mi], b0, acc0[mi][ni]);
        if constexpr (DUAL){
          bf16x8 b1 = *(const bf16x8*)&Bs1[(wn*64 + ni*16 + l15)*32 + lg*8];
          #pragma unroll
          for (int mi=0;mi<4;mi++) acc1[mi][ni] = mfma16b(af[mi], b1, acc1[mi][ni]);
        }
      }
    }
    __syncthreads();
  }

  #pragma unroll
  for (int mi=0;mi<4;mi++){
    #pragma unroll
    for (int ni=0;ni<4;ni++){
      #pragma unroll
      for (int i=0;i<4;i++){
        int rloc = wm*64 + mi*16 + 4*lg + i;
        int col  = nBase + wn*64 + ni*16 + l15;
        float v = acc0[mi][ni][i];
        if constexpr (MODE==1){
          size_t idx = (size_t)(mBase + rloc)*N + col;
          ((float*)Cout)[idx] = v*oscale + (resid ? resid[idx] : 0.0f);
        } else if constexpr (MODE==2){
          float u = acc1[mi][ni][i];
          float sv = v/(1.0f+__expf(-v))*u;
          ((bf16u*)Cout)[(size_t)(mBase + rloc)*N + col] = f2bf(sv);
        } else if constexpr (MODE==3){
          if (rloc < rows){
            float u = acc1[mi][ni][i];
            float sv = v/(1.0f+__expf(-v))*u;
            ((bf16u*)Cout)[(size_t)(slotBase + rloc)*N + col] = f2bf(sv);
          }
        } else {
          if (rloc < rows){
            ((bf16u*)Cout)[(size_t)(slotBase + rloc)*N + col] = f2bf(v);
          }
        }
      }
    }
  }
}

// ---------------- flash attention, causal GQA, f16 split-precision
__global__ __launch_bounds__(256) void attn_kernel(
    const u16* __restrict__ qh, const u16* __restrict__ ql,
    const u16* __restrict__ kh, const u16* __restrict__ kl,
    const u16* __restrict__ vth, const u16* __restrict__ vtl,
    u16* __restrict__ aoh, u16* __restrict__ aol)
{
  int qb = blockIdx.x*64;
  int bh = blockIdx.y;
  int b = bh >> 4, h = bh & 15, kvh = h >> 2;
  int tid = threadIdx.x, wave = tid>>6, lane = tid&63, l15 = lane&15, lg = lane>>4;

  __shared__ u16 Ksh[64*136];
  __shared__ u16 Ksl[64*136];
  __shared__ u16 Vsh[128*72];
  __shared__ u16 Vsl[128*72];
  __shared__ u16 Psh[4][16*72];
  __shared__ u16 Psl[4][16*72];

  size_t qrow = (size_t)(b*S_N + qb + wave*16 + l15)*QD_N + h*D_N;
  f16x8 qfh[4], qfl[4];
  #pragma unroll
  for (int ds=0; ds<4; ds++){
    qfh[ds] = *(const f16x8*)(qh + qrow + ds*32 + lg*8);
    qfl[ds] = *(const f16x8*)(ql + qrow + ds*32 + lg*8);
  }

  f32x4 zero4 = {0.f,0.f,0.f,0.f};
  f32x4 accO[8];
  #pragma unroll
  for (int dc=0; dc<8; dc++) accO[dc] = zero4;
  float mrun[4], lrun[4];
  #pragma unroll
  for (int i=0;i<4;i++){ mrun[i] = -3.0e38f; lrun[i] = 0.0f; }

  const float SC_S = 0.08838834764831845f * (1.0f/(SC_QK*SC_QK));
  int nkt = (qb >> 6) + 1;
  for (int kt=0; kt<nkt; kt++){
    #pragma unroll
    for (int pp=0; pp<4; pp++){
      int r = pp*16 + (tid>>4), c = (tid&15)*8;
      size_t go = (size_t)(b*S_N + kt*64 + r)*KD_N + kvh*D_N + c;
      *(f16x8*)&Ksh[r*136 + c] = *(const f16x8*)(kh + go);
      *(f16x8*)&Ksl[r*136 + c] = *(const f16x8*)(kl + go);
    }
    #pragma unroll
    for (int pp=0; pp<4; pp++){
      int r = pp*32 + (tid>>3), c = (tid&7)*8;
      size_t go = ((size_t)(b*HKV_N + kvh)*D_N + r)*S_N + kt*64 + c;
      *(f16x8*)&Vsh[r*72 + c] = *(const f16x8*)(vth + go);
      *(f16x8*)&Vsl[r*72 + c] = *(const f16x8*)(vtl + go);
    }
    __syncthreads();

    f32x4 sacc[4];
    #pragma unroll
    for (int kc=0;kc<4;kc++){
      sacc[kc] = zero4;
      #pragma unroll
      for (int ds=0; ds<4; ds++){
        f16x8 kfh = *(const f16x8*)&Ksh[(kc*16 + l15)*136 + ds*32 + lg*8];
        f16x8 kfl = *(const f16x8*)&Ksl[(kc*16 + l15)*136 + ds*32 + lg*8];
        sacc[kc] = mfma16h(qfh[ds], kfh, sacc[kc]);
        sacc[kc] = mfma16h(qfh[ds], kfl, sacc[kc]);
        sacc[kc] = mfma16h(qfl[ds], kfh, sacc[kc]);
      }
    }

    float pv[4][4];
    bool last = (kt == nkt-1);
    #pragma unroll
    for (int kc=0;kc<4;kc++)
      #pragma unroll
      for (int i=0;i<4;i++){
        float sv = sacc[kc][i] * SC_S;
        if (last){
          int kg = kt*64 + kc*16 + l15;
          int qg = qb + wave*16 + 4*lg + i;
          if (kg > qg) sv = -3.0e38f;
        }
        pv[kc][i] = sv;
      }

    #pragma unroll
    for (int i=0;i<4;i++){
      float mx = fmaxf(fmaxf(pv[0][i],pv[1][i]),fmaxf(pv[2][i],pv[3][i]));
      #pragma unroll
      for (int mm=1; mm<16; mm<<=1) mx = fmaxf(mx, __shfl_xor(mx, mm, 64));
      float mnew = fmaxf(mrun[i], mx);
      float corr = exp2f((mrun[i]-mnew)*1.44269504f);
      float ps = 0.f;
      #pragma unroll
      for (int kc=0;kc<4;kc++){
        float p = exp2f((pv[kc][i]-mnew)*1.44269504f);
        pv[kc][i] = p; ps += p;
      }
      #pragma unroll
      for (int mm=1; mm<16; mm<<=1) ps += __shfl_xor(ps, mm, 64);
      lrun[i] = lrun[i]*corr + ps;
      mrun[i] = mnew;
      #pragma unroll
      for (int dc=0;dc<8;dc++) accO[dc][i] *= corr;
    }

    #pragma unroll
    for (int kc=0;kc<4;kc++)
      #pragma unroll
      for (int i=0;i<4;i++){
        u16 hh, ll; split2h(pv[kc][i]*SC_P, hh, ll);
        Psh[wave][(4*lg+i)*72 + kc*16 + l15] = hh;
        Psl[wave][(4*lg+i)*72 + kc*16 + l15] = ll;
      }
    asm volatile("s_waitcnt lgkmcnt(0)" ::: "memory");
    __builtin_amdgcn_sched_barrier(0);

    #pragma unroll
    for (int ks=0; ks<2; ks++){
      f16x8 pfh = *(const f16x8*)&Psh[wave][l15*72 + ks*32 + lg*8];
      f16x8 pfl = *(const f16x8*)&Psl[wave][l15*72 + ks*32 + lg*8];
      #pragma unroll
      for (int dc=0; dc<8; dc++){
        f16x8 vfh = *(const f16x8*)&Vsh[(dc*16 + l15)*72 + ks*32 + lg*8];
        f16x8 vfl = *(const f16x8*)&Vsl[(dc*16 + l15)*72 + ks*32 + lg*8];
        accO[dc] = mfma16h(pfh, vfh, accO[dc]);
        accO[dc] = mfma16h(pfh, vfl, accO[dc]);
        accO[dc] = mfma16h(pfl, vfh, accO[dc]);
      }
    }
    __syncthreads();
  }

  // accO is scaled by SC_P*SC_V = 2^23; store ao*SC_QK(2048) halves => accO/(4096*lrun)
  #pragma unroll
  for (int i=0;i<4;i++){
    float inv = 1.0f / (4096.0f * lrun[i]);
    size_t orow = (size_t)(b*S_N + qb + wave*16 + 4*lg + i)*QD_N + h*D_N;
    #pragma unroll
    for (int dc=0; dc<8; dc++){
      u16 hh, ll; split2h(accO[dc][i]*inv, hh, ll);
      aoh[orow + dc*16 + l15] = hh;
      aol[orow + dc*16 + l15] = ll;
    }
  }
}

// ---------------- router: fp32 rms-norm + coalesced fp32 dot (gwT [E][H]) + sigmoid + top-4
__global__ __launch_bounds__(256) void router_kernel(
    const float* __restrict__ resid2, const float* __restrict__ ln2w,
    const float* __restrict__ gwT, const float* __restrict__ ebias,
    int* __restrict__ tkIdx, float* __restrict__ tkW, int* __restrict__ counts)
{
  int t = blockIdx.x, tid = threadIdx.x;
  __shared__ float xs[H_N];
  __shared__ float red[4];
  __shared__ float sc[E_N];
  const float4* x4 = (const float4*)(resid2 + (size_t)t*H_N);
  float4 a = x4[2*tid], b = x4[2*tid+1];
  float ss = a.x*a.x+a.y*a.y+a.z*a.z+a.w*a.w + b.x*b.x+b.y*b.y+b.z*b.z+b.w*b.w;
  #pragma unroll
  for (int m=32;m>=1;m>>=1) ss += __shfl_xor(ss,m,64);
  if ((tid&63)==0) red[tid>>6]=ss;
  __syncthreads();
  float scale = rsqrtf((red[0]+red[1]+red[2]+red[3])*(1.0f/H_N) + 1e-6f);
  const float4* w4 = (const float4*)ln2w;
  float4 wa = w4[2*tid], wb = w4[2*tid+1];
  xs[tid*8+0]=a.x*scale*wa.x; xs[tid*8+1]=a.y*scale*wa.y;
  xs[tid*8+2]=a.z*scale*wa.z; xs[tid*8+3]=a.w*scale*wa.w;
  xs[tid*8+4]=b.x*scale*wb.x; xs[tid*8+5]=b.y*scale*wb.y;
  xs[tid*8+6]=b.z*scale*wb.z; xs[tid*8+7]=b.w*scale*wb.w;
  __syncthreads();
  int wave = tid>>6, lane = tid&63;
  const float4* xv4 = (const float4*)xs;
  #pragma unroll
  for (int ei=0; ei<8; ei++){
    int e = wave*8 + ei;
    const float4* g4 = (const float4*)(gwT + (size_t)e*H_N);
    float acc = 0.f;
    #pragma unroll
    for (int it=0; it<8; it++){
      int idx = it*64 + lane;
      float4 g = g4[idx], xv = xv4[idx];
      acc += g.x*xv.x + g.y*xv.y + g.z*xv.z + g.w*xv.w;
    }
    #pragma unroll
    for (int m=32;m>=1;m>>=1) acc += __shfl_xor(acc,m,64);
    if (lane==0) sc[e] = 1.0f/(1.0f+__expf(-acc));
  }
  __syncthreads();
  if (tid==0){
    float sb[E_N];
    #pragma unroll
    for (int e2=0;e2<E_N;e2++) sb[e2] = sc[e2]+ebias[e2];
    int ch[4]; float wv[4]; float wsum=0.f;
    for (int j=0;j<4;j++){
      int best=0; float bv=-3.0e38f;
      for (int e2=0;e2<E_N;e2++) if (sb[e2] > bv){ bv=sb[e2]; best=e2; }
      ch[j]=best; wv[j]=sc[best]; wsum+=sc[best]; sb[best]=-3.0e38f;
    }
    float invs = 1.0f/wsum;
    for (int j=0;j<4;j++){
      tkIdx[t*4+j]=ch[j]; tkW[t*4+j]=wv[j]*invs;
      atomicAdd(&counts[ch[j]], 1);
    }
  }
}

// ---------------- deterministic capacity ranking (stable order by flat index)
__global__ void moe_count_kernel(const int* __restrict__ tki, int* __restrict__ G){
  __shared__ int cnt[E_N];
  int g = blockIdx.x, t = threadIdx.x;
  if (t < E_N) cnt[t] = 0;
  __syncthreads();
  atomicAdd(&cnt[tki[g*RGRP + t]], 1);
  __syncthreads();
  if (t < E_N) G[g*E_N + t] = cnt[t];
}

__global__ void moe_scan_kernel(const int* __restrict__ G, int* __restrict__ base,
                                int* __restrict__ starts){
  __shared__ int tot[E_N];
  int e = threadIdx.x;
  if (e < E_N){
    int run = 0;
    for (int g=0; g<NGRP; g++){ base[g*E_N+e] = run; run += G[g*E_N+e]; }
    tot[e] = run < CAP_N ? run : CAP_N;
  }
  __syncthreads();
  if (e==0){
    int run=0;
    for (int x=0; x<E_N; x++){ starts[x]=run; run+=tot[x]; }
  }
}

__global__ void moe_assign_kernel(const int* __restrict__ tki,
                                  const int* __restrict__ base, const int* __restrict__ starts,
                                  int* __restrict__ ptok, int* __restrict__ tok2slot){
  __shared__ int eL[RGRP];
  int g = blockIdx.x, t = threadIdx.x;
  int f = g*RGRP + t;
  int e = tki[f];
  eL[t] = e;
  __syncthreads();
  int r = 0;
  for (int j=0; j<RGRP; j++) r += ((j < t) && (eL[j]==e)) ? 1 : 0;
  int pos = base[g*E_N + e] + r;
  if (pos < CAP_N){
    int slot = starts[e] + pos;
    ptok[slot] = f >> 2;
    tok2slot[f] = slot;
  } else {
    tok2slot[f] = -1;
  }
}

// ---------------- combine: out[t] += sum_j w_j * obuf[slot_j]   (out already = shared+resid)
__global__ __launch_bounds__(256) void moe_combine(const int* __restrict__ tok2slot,
                                                   const float* __restrict__ tkw,
                                                   const bf16u* __restrict__ obuf,
                                                   float* __restrict__ outp){
  int t = blockIdx.x;
  int c0 = threadIdx.x*8;
  float acc[8];
  float4* o4 = (float4*)(outp + (size_t)t*H_N + c0);
  float4 v0 = o4[0], v1 = o4[1];
  acc[0]=v0.x; acc[1]=v0.y; acc[2]=v0.z; acc[3]=v0.w;
  acc[4]=v1.x; acc[5]=v1.y; acc[6]=v1.z; acc[7]=v1.w;
  #pragma unroll
  for (int j=0;j<4;j++){
    int slot = tok2slot[t*4+j];
    if (slot >= 0){
      float w = tkw[t*4+j];
      bf16x8 ob = *(const bf16x8*)(obuf + (size_t)slot*H_N + c0);
      #pragma unroll
      for (int q=0;q<8;q++) acc[q] += w * bf2f((bf16u)ob[q]);
    }
  }
  v0.x=acc[0]; v0.y=acc[1]; v0.z=acc[2]; v0.w=acc[3];
  v1.x=acc[4]; v1.y=acc[5]; v1.z=acc[6]; v1.w=acc[7];
  o4[0]=v0; o4[1]=v1;
}

extern "C" void kernel_launch(void* const* d_in, const int* in_sizes, int n_in,
                              void* d_out, int out_size, void* d_ws, size_t ws_size,
                              hipStream_t stream) {
  (void)in_sizes; (void)n_in; (void)out_size; (void)ws_size;
  const float* hidden    = (const float*)d_in[0];
  const int*   positions = (const int*)d_in[1];
  const float* ln1w = (const float*)d_in[2];
  const float* ln2w = (const float*)d_in[3];
  const float* wq   = (const float*)d_in[4];
  const float* wk   = (const float*)d_in[5];
  const float* wv   = (const float*)d_in[6];
  const float* wo   = (const float*)d_in[7];
  const float* qnw  = (const float*)d_in[8];
  const float* knw  = (const float*)d_in[9];
  const float* gatew= (const float*)d_in[10];
  const float* ebias= (const float*)d_in[11];
  const float* wge  = (const float*)d_in[12];
  const float* wue  = (const float*)d_in[13];
  const float* wde  = (const float*)d_in[14];
  const float* wsg  = (const float*)d_in[15];
  const float* wsu  = (const float*)d_in[16];
  const float* wsd  = (const float*)d_in[17];
  float* outp = (float*)d_out;

  char* wsb = (char*)d_ws;
  size_t off = 0;
  auto take = [&](size_t bytes)->char*{
    char* p = wsb + off; off += (bytes + 255) & ~(size_t)255; return p;
  };
  u16* qkvTh = (u16*)take(3072ull*2048*2);   // rows: 0..2047 wq, 2048..2559 wk, 2560..3071 wv
  u16* qkvTl = (u16*)take(3072ull*2048*2);
  u16* woTh = (u16*)take(2048ull*2048*2);
  u16* woTl = (u16*)take(2048ull*2048*2);
  u16* wsgT = (u16*)take(1024ull*2048*2);
  u16* wsuT = (u16*)take(1024ull*2048*2);
  u16* wsdT = (u16*)take(2048ull*1024*2);
  u16* wgeT = (u16*)take(32ull*512*2048*2);
  u16* wueT = (u16*)take(32ull*512*2048*2);
  u16* wdeT = (u16*)take(32ull*2048*512*2);
  float* gwT = (float*)take(32ull*2048*4);
  u16* h1h  = (u16*)take((size_t)T_N*H_N*2);
  u16* h1l  = (u16*)take((size_t)T_N*H_N*2);
  float* qkv32 = (float*)take((size_t)T_N*QKV_N*4);
  u16* qHh  = (u16*)take((size_t)T_N*QD_N*2);
  u16* qHl  = (u16*)take((size_t)T_N*QD_N*2);
  u16* kHh  = (u16*)take((size_t)T_N*KD_N*2);
  u16* kHl  = (u16*)take((size_t)T_N*KD_N*2);
  u16* vtHh = (u16*)take((size_t)T_N*KD_N*2);
  u16* vtHl = (u16*)take((size_t)T_N*KD_N*2);
  u16* aoh  = (u16*)take((size_t)T_N*QD_N*2);
  u16* aol  = (u16*)take((size_t)T_N*QD_N*2);
  float* resid2=(float*)take((size_t)T_N*H_N*4);
  u16* h2   = (u16*)take((size_t)T_N*H_N*2);
  u16* interS=(u16*)take((size_t)T_N*SIM_N*2);
  u16* minter=(u16*)take((size_t)NFLAT*IM_N*2);
  bf16u* obuf = (bf16u*)take((size_t)NFLAT*H_N*2);
  int*   tki  = (int*)take((size_t)NFLAT*4);
  float* tkw  = (float*)take((size_t)NFLAT*4);
  int*   counts=(int*)take(E_N*4);
  int*   Gcnt = (int*)take((size_t)NGRP*E_N*4);
  int*   Gbase= (int*)take((size_t)NGRP*E_N*4);
  int*   starts=(int*)take(E_N*4);
  int*   ptok = (int*)take((size_t)NFLAT*4);
  int*   tok2slot = (int*)take((size_t)NFLAT*4);

  hipMemsetAsync(counts, 0, 256, stream);

  dim3 tb(32,8);
  transpose_cvt_split16<<<dim3(64,64,1), tb, 0, stream>>>(wq, qkvTh, qkvTl, 2048, 2048, SC_W);
  transpose_cvt_split16<<<dim3(64,16,1), tb, 0, stream>>>(wk, qkvTh + 2048ull*2048, qkvTl + 2048ull*2048, 2048, 512, SC_W);
  transpose_cvt_split16<<<dim3(64,16,1), tb, 0, stream>>>(wv, qkvTh + 2560ull*2048, qkvTl + 2560ull*2048, 2048, 512, SC_W);
  transpose_cvt_split16<<<dim3(64,64,1), tb, 0, stream>>>(wo, woTh, woTl, 2048, 2048, SC_W);
  transpose_cvt<<<dim3(64,32,1), tb, 0, stream>>>(wsg, (bf16u*)wsgT, 2048, 1024);
  transpose_cvt<<<dim3(64,32,1), tb, 0, stream>>>(wsu, (bf16u*)wsuT, 2048, 1024);
  transpose_cvt<<<dim3(32,64,1), tb, 0, stream>>>(wsd, (bf16u*)wsdT, 1024, 2048);
  transpose_cvt<<<dim3(64,16,32), tb, 0, stream>>>(wge, (bf16u*)wgeT, 2048, 512);
  transpose_cvt<<<dim3(64,16,32), tb, 0, stream>>>(wue, (bf16u*)wueT, 2048, 512);
  transpose_cvt<<<dim3(16,64,32), tb, 0, stream>>>(wde, (bf16u*)wdeT, 512, 2048);
  transpose_f32<<<dim3(64,1,1), tb, 0, stream>>>(gatew, gwT, 2048, 32);

  rmsnorm_f16split<<<T_N, 256, 0, stream>>>(hidden, ln1w, h1h, h1l);
  gemm_bt<1,true><<<dim3(16,24), 256, 0, stream>>>(h1h, h1l, qkvTh, qkvTl, nullptr, qkv32, nullptr, OSC_QKV, T_N, QKV_N, H_N, nullptr,nullptr,nullptr);
  qknorm_rope_split<<<dim3(T_N,20), 64, 0, stream>>>(qkv32, qnw, knw, positions, qHh, qHl, kHh, kHl);
  transpose_v_split<<<dim3(32,4,8), tb, 0, stream>>>(qkv32, vtHh, vtHl);
  attn_kernel<<<dim3(16,32), 256, 0, stream>>>(qHh, qHl, kHh, kHl, vtHh, vtHl, aoh, aol);
  gemm_bt<1,true><<<dim3(16,16), 256, 0, stream>>>(aoh, aol, woTh, woTl, nullptr, resid2, hidden, OSC_OPJ, T_N, H_N, QD_N, nullptr,nullptr,nullptr);
  rmsnorm_bf16<<<T_N, 256, 0, stream>>>(resid2, ln2w, (bf16u*)h2);
  gemm_bt<2,false><<<dim3(16,8), 256, 0, stream>>>(h2, nullptr, wsgT, nullptr, wsuT, interS, nullptr, 1.0f, T_N, SIM_N, H_N, nullptr,nullptr,nullptr);
  gemm_bt<1,false><<<dim3(16,16), 256, 0, stream>>>(interS, nullptr, wsdT, nullptr, nullptr, outp, resid2, 1.0f, T_N, H_N, SIM_N, nullptr,nullptr,nullptr);
  router_kernel<<<T_N, 256, 0, stream>>>(resid2, ln2w, gwT, ebias, tki, tkw, counts);
  moe_count_kernel<<<NGRP, RGRP, 0, stream>>>(tki, Gcnt);
  moe_scan_kernel<<<1, 64, 0, stream>>>(Gcnt, Gbase, starts);
  moe_assign_kernel<<<NGRP, RGRP, 0, stream>>>(tki, Gbase, starts, ptok, tok2slot);
  gemm_bt<3,false><<<dim3(4,4,32), 256, 0, stream>>>(h2, nullptr, wgeT, nullptr, wueT, minter, nullptr, 1.0f, 0, IM_N, H_N, starts, counts, ptok);
  gemm_bt<4,false><<<dim3(4,16,32), 256, 0, stream>>>(minter, nullptr, wdeT, nullptr, nullptr, obuf, nullptr, 1.0f, 0, H_N, IM_N, starts, counts, ptok);
  moe_combine<<<T_N, 256, 0, stream>>>(tok2slot, tkw, obuf, outp);
}